// Round 1
// baseline (900.347 us; speedup 1.0000x reference)
//
#include <hip/hip_runtime.h>
#include <hip/hip_bf16.h>
#include <cstdint>
#include <cstddef>

#define HDIM  128
#define NCLS  5
#define NLEAF 65536

__device__ __forceinline__ float sigf(float x) {
    return 1.0f / (1.0f + __expf(-x));
}

__device__ __forceinline__ float dot4acc(float4 e, float w0, float w1, float w2, float w3, float acc) {
    acc = fmaf(e.x, w0, acc);
    acc = fmaf(e.y, w1, acc);
    acc = fmaf(e.z, w2, acc);
    acc = fmaf(e.w, w3, acc);
    return acc;
}

// ---------------------------------------------------------------------------
// Leaf kernel: e = emb[words]; i,o,u gates; c = i*u; h = o*relu(c)
// block = 512 threads: j = tid&127 (output col), q = tid>>7 (row group)
// ROWS rows per block, RPT = ROWS/4 rows per thread.
// ---------------------------------------------------------------------------
template<int ROWS>
__global__ __launch_bounds__(512)
void leaf_kernel(const int* __restrict__ words,
                 const float* __restrict__ emb,
                 const float* __restrict__ Wi, const float* __restrict__ bi,
                 const float* __restrict__ Wo, const float* __restrict__ bo,
                 const float* __restrict__ Wu, const float* __restrict__ bu,
                 float* __restrict__ Hout, float* __restrict__ Cout, int N)
{
    __shared__ float e_lds[ROWS][HDIM];
    const int tid = threadIdx.x;
    const int rb  = blockIdx.x * ROWS;

    // stage e tile (gather rows of emb) as float4
    for (int idx = tid; idx < ROWS * (HDIM / 4); idx += 512) {
        int lr = idx >> 5;            // HDIM/4 = 32 chunks per row
        int c4 = (idx & 31) << 2;
        int r  = rb + lr;
        float4 v = make_float4(0.f, 0.f, 0.f, 0.f);
        if (r < N) {
            int w = words[r];
            v = *reinterpret_cast<const float4*>(&emb[(size_t)w * HDIM + c4]);
        }
        *reinterpret_cast<float4*>(&e_lds[lr][c4]) = v;
    }
    __syncthreads();

    const int j = tid & (HDIM - 1);
    const int q = tid >> 7;
    constexpr int RPT = ROWS / 4;

    float ai[RPT], ao[RPT], au[RPT];
#pragma unroll
    for (int rr = 0; rr < RPT; ++rr) { ai[rr] = 0.f; ao[rr] = 0.f; au[rr] = 0.f; }

#pragma unroll 2
    for (int k0 = 0; k0 < HDIM; k0 += 4) {
        float wi0 = Wi[(k0 + 0) * HDIM + j], wi1 = Wi[(k0 + 1) * HDIM + j],
              wi2 = Wi[(k0 + 2) * HDIM + j], wi3 = Wi[(k0 + 3) * HDIM + j];
        float wo0 = Wo[(k0 + 0) * HDIM + j], wo1 = Wo[(k0 + 1) * HDIM + j],
              wo2 = Wo[(k0 + 2) * HDIM + j], wo3 = Wo[(k0 + 3) * HDIM + j];
        float wu0 = Wu[(k0 + 0) * HDIM + j], wu1 = Wu[(k0 + 1) * HDIM + j],
              wu2 = Wu[(k0 + 2) * HDIM + j], wu3 = Wu[(k0 + 3) * HDIM + j];
#pragma unroll
        for (int rr = 0; rr < RPT; ++rr) {
            int lr = q + (rr << 2);
            float4 e = *reinterpret_cast<const float4*>(&e_lds[lr][k0]);
            ai[rr] = dot4acc(e, wi0, wi1, wi2, wi3, ai[rr]);
            ao[rr] = dot4acc(e, wo0, wo1, wo2, wo3, ao[rr]);
            au[rr] = dot4acc(e, wu0, wu1, wu2, wu3, au[rr]);
        }
    }

#pragma unroll
    for (int rr = 0; rr < RPT; ++rr) {
        int r = rb + q + (rr << 2);
        if (r < N) {
            float iv = sigf(ai[rr] + bi[j]);
            float ov = sigf(ao[rr] + bo[j]);
            float uv = fmaxf(au[rr] + bu[j], 0.f);
            float c  = iv * uv;
            float h  = ov * fmaxf(c, 0.f);
            Hout[(size_t)r * HDIM + j] = h;
            Cout[(size_t)r * HDIM + j] = c;
        }
    }
}

// ---------------------------------------------------------------------------
// Level kernel: eN = [lH|rH]; i,o,u over K=256; f1 over lH; f2 over rH;
// c = i*u + f1*lC + f2*rC; h = o*relu(c)
// ---------------------------------------------------------------------------
template<int ROWS>
__global__ __launch_bounds__(512)
void level_kernel(const float* __restrict__ Hin,   // 2n x 128
                  const float* __restrict__ Cin,   // 2n x 128
                  const float* __restrict__ Ui,  const float* __restrict__ bUi,
                  const float* __restrict__ Uo,  const float* __restrict__ bUo,
                  const float* __restrict__ Uu,  const float* __restrict__ bUu,
                  const float* __restrict__ Uf1, const float* __restrict__ bf1,
                  const float* __restrict__ Uf2, const float* __restrict__ bf2,
                  float* __restrict__ Hout, float* __restrict__ Cout, int n)
{
    __shared__ float e_lds[ROWS][2 * HDIM];
    const int tid = threadIdx.x;
    const int rb  = blockIdx.x * ROWS;

    // stage [lH|rH] tile
    for (int idx = tid; idx < ROWS * (2 * HDIM / 4); idx += 512) {
        int lr = idx >> 6;            // 64 float4-chunks per row
        int c4 = (idx & 63) << 2;
        int r  = rb + lr;
        float4 v = make_float4(0.f, 0.f, 0.f, 0.f);
        if (r < n) {
            int child = 2 * r + (c4 >= HDIM ? 1 : 0);
            int cc    = c4 & (HDIM - 1);
            v = *reinterpret_cast<const float4*>(&Hin[(size_t)child * HDIM + cc]);
        }
        *reinterpret_cast<float4*>(&e_lds[lr][c4]) = v;
    }
    __syncthreads();

    const int j = tid & (HDIM - 1);
    const int q = tid >> 7;
    constexpr int RPT = ROWS / 4;

    float ai[RPT], ao[RPT], au[RPT], af1[RPT], af2[RPT];
#pragma unroll
    for (int rr = 0; rr < RPT; ++rr) {
        ai[rr] = 0.f; ao[rr] = 0.f; au[rr] = 0.f; af1[rr] = 0.f; af2[rr] = 0.f;
    }

    // first half: k in [0,128)  (lH part: i,o,u + f1)
#pragma unroll 2
    for (int k0 = 0; k0 < HDIM; k0 += 4) {
        float wi0 = Ui[(k0 + 0) * HDIM + j], wi1 = Ui[(k0 + 1) * HDIM + j],
              wi2 = Ui[(k0 + 2) * HDIM + j], wi3 = Ui[(k0 + 3) * HDIM + j];
        float wo0 = Uo[(k0 + 0) * HDIM + j], wo1 = Uo[(k0 + 1) * HDIM + j],
              wo2 = Uo[(k0 + 2) * HDIM + j], wo3 = Uo[(k0 + 3) * HDIM + j];
        float wu0 = Uu[(k0 + 0) * HDIM + j], wu1 = Uu[(k0 + 1) * HDIM + j],
              wu2 = Uu[(k0 + 2) * HDIM + j], wu3 = Uu[(k0 + 3) * HDIM + j];
        float wf0 = Uf1[(k0 + 0) * HDIM + j], wf1 = Uf1[(k0 + 1) * HDIM + j],
              wf2 = Uf1[(k0 + 2) * HDIM + j], wf3 = Uf1[(k0 + 3) * HDIM + j];
#pragma unroll
        for (int rr = 0; rr < RPT; ++rr) {
            int lr = q + (rr << 2);
            float4 e = *reinterpret_cast<const float4*>(&e_lds[lr][k0]);
            ai[rr]  = dot4acc(e, wi0, wi1, wi2, wi3, ai[rr]);
            ao[rr]  = dot4acc(e, wo0, wo1, wo2, wo3, ao[rr]);
            au[rr]  = dot4acc(e, wu0, wu1, wu2, wu3, au[rr]);
            af1[rr] = dot4acc(e, wf0, wf1, wf2, wf3, af1[rr]);
        }
    }

    // second half: k in [128,256)  (rH part: i,o,u + f2)
#pragma unroll 2
    for (int k0 = 0; k0 < HDIM; k0 += 4) {
        float wi0 = Ui[(HDIM + k0 + 0) * HDIM + j], wi1 = Ui[(HDIM + k0 + 1) * HDIM + j],
              wi2 = Ui[(HDIM + k0 + 2) * HDIM + j], wi3 = Ui[(HDIM + k0 + 3) * HDIM + j];
        float wo0 = Uo[(HDIM + k0 + 0) * HDIM + j], wo1 = Uo[(HDIM + k0 + 1) * HDIM + j],
              wo2 = Uo[(HDIM + k0 + 2) * HDIM + j], wo3 = Uo[(HDIM + k0 + 3) * HDIM + j];
        float wu0 = Uu[(HDIM + k0 + 0) * HDIM + j], wu1 = Uu[(HDIM + k0 + 1) * HDIM + j],
              wu2 = Uu[(HDIM + k0 + 2) * HDIM + j], wu3 = Uu[(HDIM + k0 + 3) * HDIM + j];
        float wf0 = Uf2[(k0 + 0) * HDIM + j], wf1 = Uf2[(k0 + 1) * HDIM + j],
              wf2 = Uf2[(k0 + 2) * HDIM + j], wf3 = Uf2[(k0 + 3) * HDIM + j];
#pragma unroll
        for (int rr = 0; rr < RPT; ++rr) {
            int lr = q + (rr << 2);
            float4 e = *reinterpret_cast<const float4*>(&e_lds[lr][HDIM + k0]);
            ai[rr]  = dot4acc(e, wi0, wi1, wi2, wi3, ai[rr]);
            ao[rr]  = dot4acc(e, wo0, wo1, wo2, wo3, ao[rr]);
            au[rr]  = dot4acc(e, wu0, wu1, wu2, wu3, au[rr]);
            af2[rr] = dot4acc(e, wf0, wf1, wf2, wf3, af2[rr]);
        }
    }

#pragma unroll
    for (int rr = 0; rr < RPT; ++rr) {
        int r = rb + q + (rr << 2);
        if (r < n) {
            float iv = sigf(ai[rr]  + bUi[j]);
            float ov = sigf(ao[rr]  + bUo[j]);
            float uv = fmaxf(au[rr] + bUu[j], 0.f);
            float f1 = sigf(af1[rr] + bf1[j]);
            float f2 = sigf(af2[rr] + bf2[j]);
            float lC = Cin[(size_t)(2 * r)     * HDIM + j];
            float rC = Cin[(size_t)(2 * r + 1) * HDIM + j];
            float c  = fmaf(iv, uv, fmaf(f1, lC, f2 * rC));
            float h  = ov * fmaxf(c, 0.f);
            Hout[(size_t)r * HDIM + j] = h;
            Cout[(size_t)r * HDIM + j] = c;
        }
    }
}

// ---------------------------------------------------------------------------
// Projection: out[r] = h[r] @ P + bP    (one wave per row)
// ---------------------------------------------------------------------------
__global__ __launch_bounds__(256)
void proj_kernel(const float* __restrict__ Hbuf,
                 const float* __restrict__ P, const float* __restrict__ bP,
                 float* __restrict__ out, int total)
{
    int wid  = blockIdx.x * 4 + (threadIdx.x >> 6);
    int lane = threadIdx.x & 63;
    if (wid >= total) return;
    const float* h = Hbuf + (size_t)wid * HDIM;
    float h0 = h[lane];
    float h1 = h[lane + 64];
    float acc[NCLS];
#pragma unroll
    for (int c = 0; c < NCLS; ++c)
        acc[c] = fmaf(h0, P[lane * NCLS + c], h1 * P[(lane + 64) * NCLS + c]);
    for (int off = 32; off > 0; off >>= 1) {
#pragma unroll
        for (int c = 0; c < NCLS; ++c)
            acc[c] += __shfl_down(acc[c], off, 64);
    }
    if (lane == 0) {
#pragma unroll
        for (int c = 0; c < NCLS; ++c)
            out[(size_t)wid * NCLS + c] = acc[c] + bP[c];
    }
}

// ---------------------------------------------------------------------------
// Host launcher
// ws layout (f32): Hbuf[131072*128] | CA[65536*128] | CB[32768*128]  = 112 MB
// ---------------------------------------------------------------------------
extern "C" void kernel_launch(void* const* d_in, const int* in_sizes, int n_in,
                              void* d_out, int out_size, void* d_ws, size_t ws_size,
                              hipStream_t stream)
{
    const int*   words = (const int*)  d_in[0];
    const float* emb   = (const float*)d_in[1];
    const float* Wi  = (const float*)d_in[2];  const float* bi  = (const float*)d_in[3];
    const float* Wo  = (const float*)d_in[4];  const float* bo  = (const float*)d_in[5];
    const float* Wu  = (const float*)d_in[6];  const float* bu  = (const float*)d_in[7];
    const float* Ui  = (const float*)d_in[8];  const float* bUi = (const float*)d_in[9];
    const float* Uo  = (const float*)d_in[10]; const float* bUo = (const float*)d_in[11];
    const float* Uu  = (const float*)d_in[12]; const float* bUu = (const float*)d_in[13];
    const float* Uf1 = (const float*)d_in[14]; const float* bf1 = (const float*)d_in[15];
    const float* Uf2 = (const float*)d_in[16]; const float* bf2 = (const float*)d_in[17];
    const float* P   = (const float*)d_in[18]; const float* bP  = (const float*)d_in[19];
    float* out = (float*)d_out;

    float* Hbuf = (float*)d_ws;                          // 131072 rows
    float* CA   = Hbuf + (size_t)131072 * HDIM;          // 65536 rows
    float* CB   = CA   + (size_t)65536  * HDIM;          // 32768 rows

    constexpr int ROWS = 32;

    leaf_kernel<ROWS><<<NLEAF / ROWS, 512, 0, stream>>>(
        words, emb, Wi, bi, Wo, bo, Wu, bu, Hbuf, CA, NLEAF);

    const float* cin = CA;
    float*       cot = CB;
    int n_prev = NLEAF;
    int off_prev = 0;
    int off = NLEAF;
    while (n_prev > 1) {
        int m = n_prev >> 1;
        int blocks = (m + ROWS - 1) / ROWS;
        level_kernel<ROWS><<<blocks, 512, 0, stream>>>(
            Hbuf + (size_t)off_prev * HDIM, cin,
            Ui, bUi, Uo, bUo, Uu, bUu, Uf1, bf1, Uf2, bf2,
            Hbuf + (size_t)off * HDIM, cot, m);
        float* tmp = (float*)cin; cin = cot; cot = tmp;
        off_prev = off;
        off += m;
        n_prev = m;
    }

    int total = off;  // 131071
    proj_kernel<<<(total + 3) / 4, 256, 0, stream>>>(Hbuf, P, bP, out, total);
}